// Round 1
// baseline (835.239 us; speedup 1.0000x reference)
//
#include <hip/hip_runtime.h>

#define LR    0.01f
#define B1    0.9f
#define B2    0.999f
#define EPSL  1e-8f

// ---------------------------------------------------------------------------
// Pass 1: zero the gsum accumulator (lives in the mem_new slot of d_out) and
// the per-row count buffer (lives in d_ws).
// ---------------------------------------------------------------------------
__global__ void zero_kernel(float4* __restrict__ gsum4, long gsum4_n,
                            float*  __restrict__ cnt,   long cnt_n) {
    long t = (long)blockIdx.x * blockDim.x + threadIdx.x;
    long stride = (long)gridDim.x * blockDim.x;
    for (long j = t; j < gsum4_n; j += stride)
        gsum4[j] = make_float4(0.f, 0.f, 0.f, 0.f);
    for (long j = t; j < cnt_n; j += stride)
        cnt[j] = 0.f;
}

// ---------------------------------------------------------------------------
// Pass 2: scatter-add gradients. 16 threads per grad row (one float4 each).
// ---------------------------------------------------------------------------
__global__ void scatter_kernel(const int*   __restrict__ idx,
                               const float4* __restrict__ grad4,
                               float* __restrict__ gsum,
                               float* __restrict__ cnt,
                               int N) {
    int t = blockIdx.x * blockDim.x + threadIdx.x;
    int row = t >> 4;
    int q   = t & 15;
    if (row >= N) return;
    int v = idx[row];
    float4 g = grad4[(long)row * 16 + q];
    float* dst = gsum + (long)v * 64 + q * 4;
    atomicAdd(dst + 0, g.x);
    atomicAdd(dst + 1, g.y);
    atomicAdd(dst + 2, g.z);
    atomicAdd(dst + 3, g.w);
    if (q == 0) atomicAdd(cnt + v, 1.0f);
}

// ---------------------------------------------------------------------------
// Pass 3: elementwise Adam over the full table. One float4 (4 of D=64) per
// thread; wave lanes 0..15 cover one row, so cnt/step loads broadcast.
// gsum is read from the mem_new slot and overwritten in-place (same thread).
// ---------------------------------------------------------------------------
__global__ void adam_kernel(const float4* __restrict__ emb4,
                            const float*  __restrict__ step_in,
                            const float4* __restrict__ mem4,
                            const float4* __restrict__ pow4,
                            const float*  __restrict__ cnt,
                            float* __restrict__ out,
                            int V) {
    int t = blockIdx.x * blockDim.x + threadIdx.x;   // V*16 threads
    int v = t >> 4;
    int q = t & 15;
    if (v >= V) return;

    float4* emb_out  = (float4*)out;                          // [V*16] float4
    float*  step_out = out + (long)V * 64;                    // [V]
    float4* mem_out  = (float4*)(out + (long)V * 64 + V);     // [V*16] float4 (holds gsum now)
    float4* pow_out  = mem_out + (long)V * 16;                // [V*16] float4

    float c = cnt[v];
    bool touched = (c > 0.f);

    float4 gs = mem_out[t];     // accumulated gradient sum
    float4 e  = emb4[t];
    float4 m  = mem4[t];
    float4 p  = pow4[t];
    float s_old = step_in[v];
    float s_new = touched ? s_old + 1.f : s_old;

    float inv_c = touched ? 1.f / c : 0.f;
    float d1 = touched ? 1.f - powf(B1, s_new) : 1.f;
    float d2 = touched ? 1.f - powf(B2, s_new) : 1.f;
    float inv_d1 = 1.f / d1;
    float inv_d2 = 1.f / d2;

    float4 m_new, p_new, e_new;
    {
        float gv, mn, pn, upd;
        // x
        gv = gs.x * inv_c;
        mn = touched ? B1 * m.x + (1.f - B1) * gv : m.x;
        pn = touched ? B2 * p.x + (1.f - B2) * gv * gv : p.x;
        upd = LR * (mn * inv_d1) / (sqrtf(pn * inv_d2) + EPSL);
        m_new.x = mn; p_new.x = pn; e_new.x = touched ? e.x - upd : e.x;
        // y
        gv = gs.y * inv_c;
        mn = touched ? B1 * m.y + (1.f - B1) * gv : m.y;
        pn = touched ? B2 * p.y + (1.f - B2) * gv * gv : p.y;
        upd = LR * (mn * inv_d1) / (sqrtf(pn * inv_d2) + EPSL);
        m_new.y = mn; p_new.y = pn; e_new.y = touched ? e.y - upd : e.y;
        // z
        gv = gs.z * inv_c;
        mn = touched ? B1 * m.z + (1.f - B1) * gv : m.z;
        pn = touched ? B2 * p.z + (1.f - B2) * gv * gv : p.z;
        upd = LR * (mn * inv_d1) / (sqrtf(pn * inv_d2) + EPSL);
        m_new.z = mn; p_new.z = pn; e_new.z = touched ? e.z - upd : e.z;
        // w
        gv = gs.w * inv_c;
        mn = touched ? B1 * m.w + (1.f - B1) * gv : m.w;
        pn = touched ? B2 * p.w + (1.f - B2) * gv * gv : p.w;
        upd = LR * (mn * inv_d1) / (sqrtf(pn * inv_d2) + EPSL);
        m_new.w = mn; p_new.w = pn; e_new.w = touched ? e.w - upd : e.w;
    }

    emb_out[t] = e_new;
    mem_out[t] = m_new;
    pow_out[t] = p_new;
    if (q == 0) step_out[v] = s_new;
}

extern "C" void kernel_launch(void* const* d_in, const int* in_sizes, int n_in,
                              void* d_out, int out_size, void* d_ws, size_t ws_size,
                              hipStream_t stream) {
    const int*    idx  = (const int*)   d_in[0];
    const float*  grad = (const float*) d_in[1];
    const float*  emb  = (const float*) d_in[2];
    const float*  step = (const float*) d_in[3];
    const float*  mem  = (const float*) d_in[4];
    const float*  pw   = (const float*) d_in[5];

    const int N = in_sizes[0];        // 524288
    const int V = in_sizes[3];        // 1000000
    const int Dd = 64;

    float* out = (float*)d_out;
    float* cnt = (float*)d_ws;                         // V floats (4 MB)
    float* gsum = out + (long)V * Dd + V;              // mem_new slot doubles as gsum

    // Pass 1: zero accumulators
    {
        long gsum4_n = (long)V * Dd / 4;               // 16M float4
        int blocks = 2048, threads = 256;
        zero_kernel<<<blocks, threads, 0, stream>>>((float4*)gsum, gsum4_n, cnt, (long)V);
    }

    // Pass 2: scatter-add
    {
        long total = (long)N * 16;
        int threads = 256;
        int blocks = (int)((total + threads - 1) / threads);
        scatter_kernel<<<blocks, threads, 0, stream>>>(idx, (const float4*)grad, gsum, cnt, N);
    }

    // Pass 3: Adam elementwise
    {
        long total = (long)V * 16;
        int threads = 256;
        int blocks = (int)((total + threads - 1) / threads);
        adam_kernel<<<blocks, threads, 0, stream>>>((const float4*)emb, step,
                                                    (const float4*)mem, (const float4*)pw,
                                                    cnt, out, V);
    }
}

// Round 2
// 363.398 us; speedup vs baseline: 2.2984x; 2.2984x over previous
//
#include <hip/hip_runtime.h>

#define LR    0.01f
#define B1    0.9f
#define B2    0.999f
#define EPSL  1e-8f

#define SCAN_CHUNK   1024
#define SCAN_THREADS 256

// log2(0.9), log2(0.999)
#define LOG2_B1 (-0.15200309344504997f)
#define LOG2_B2 (-0.0014434251880582487f)

// ---------------------------------------------------------------------------
// 1. zero the per-index counters
// ---------------------------------------------------------------------------
__global__ void zero_cnt_kernel(int* __restrict__ cnt, int V) {
    int t = blockIdx.x * blockDim.x + threadIdx.x;
    int stride = gridDim.x * blockDim.x;
    for (int i = t; i < V; i += stride) cnt[i] = 0;
}

// ---------------------------------------------------------------------------
// 2. count occurrences; record each row's slot within its bin
// ---------------------------------------------------------------------------
__global__ void count_kernel(const int* __restrict__ idx,
                             int* __restrict__ cnt,
                             int* __restrict__ rowpos, int N) {
    int i = blockIdx.x * blockDim.x + threadIdx.x;
    if (i >= N) return;
    int v = idx[i];
    rowpos[i] = atomicAdd(&cnt[v], 1);
}

// ---------------------------------------------------------------------------
// 3. per-chunk sums of cnt (chunk = 1024 elements, 256 threads x 4)
// ---------------------------------------------------------------------------
__global__ void block_sum_kernel(const int* __restrict__ cnt,
                                 int* __restrict__ bsum, int V) {
    __shared__ int sh[SCAN_THREADS];
    int b = blockIdx.x, t = threadIdx.x;
    int base = b * SCAN_CHUNK + t * 4;
    int s = 0;
    #pragma unroll
    for (int k = 0; k < 4; ++k) {
        int i = base + k;
        if (i < V) s += cnt[i];
    }
    sh[t] = s;
    __syncthreads();
    for (int d = 128; d > 0; d >>= 1) {
        if (t < d) sh[t] += sh[t + d];
        __syncthreads();
    }
    if (t == 0) bsum[b] = sh[0];
}

// ---------------------------------------------------------------------------
// 4. exclusive scan of chunk sums (single block; nB <= 1024)
// ---------------------------------------------------------------------------
__global__ void scan_bsum_kernel(const int* __restrict__ bsum,
                                 int* __restrict__ bpre, int nB) {
    __shared__ int sh[1024];
    int t = threadIdx.x;
    int own = (t < nB) ? bsum[t] : 0;
    sh[t] = own;
    __syncthreads();
    for (int d = 1; d < 1024; d <<= 1) {
        int add = (t >= d) ? sh[t - d] : 0;
        __syncthreads();
        sh[t] += add;
        __syncthreads();
    }
    if (t < nB) bpre[t] = sh[t] - own;
}

// ---------------------------------------------------------------------------
// 5. apply scan: off[i] = global exclusive prefix of cnt
// ---------------------------------------------------------------------------
__global__ void scan_apply_kernel(const int* __restrict__ cnt,
                                  const int* __restrict__ bpre,
                                  int* __restrict__ off, int V) {
    __shared__ int sh[SCAN_THREADS];
    int b = blockIdx.x, t = threadIdx.x;
    int base = b * SCAN_CHUNK + t * 4;
    int c[4];
    int s = 0;
    #pragma unroll
    for (int k = 0; k < 4; ++k) {
        int i = base + k;
        c[k] = (i < V) ? cnt[i] : 0;
        s += c[k];
    }
    int own = s;
    sh[t] = s;
    __syncthreads();
    for (int d = 1; d < 256; d <<= 1) {
        int add = (t >= d) ? sh[t - d] : 0;
        __syncthreads();
        sh[t] += add;
        __syncthreads();
    }
    int pre = bpre[b] + (sh[t] - own);
    #pragma unroll
    for (int k = 0; k < 4; ++k) {
        int i = base + k;
        if (i < V) off[i] = pre;
        pre += c[k];
    }
}

// ---------------------------------------------------------------------------
// 6. fill CSR row-id list (no atomics; slots from rowpos)
// ---------------------------------------------------------------------------
__global__ void fill_kernel(const int* __restrict__ idx,
                            const int* __restrict__ rowpos,
                            const int* __restrict__ off,
                            int* __restrict__ rowids, int N) {
    int i = blockIdx.x * blockDim.x + threadIdx.x;
    if (i >= N) return;
    int v = idx[i];
    rowids[off[v] + rowpos[i]] = i;
}

// ---------------------------------------------------------------------------
// 7. fused gather + Adam over the full table. One float4 per thread,
//    16 threads per row.
// ---------------------------------------------------------------------------
__global__ void adam_kernel(const float4* __restrict__ emb4,
                            const float*  __restrict__ step_in,
                            const float4* __restrict__ mem4,
                            const float4* __restrict__ pow4,
                            const float4* __restrict__ grad4,
                            const int*    __restrict__ cnt,
                            const int*    __restrict__ off,
                            const int*    __restrict__ rowids,
                            float* __restrict__ out,
                            int V) {
    int t = blockIdx.x * blockDim.x + threadIdx.x;   // V*16 threads
    int v = t >> 4;
    int q = t & 15;
    if (v >= V) return;

    float4* emb_out  = (float4*)out;                          // [V*16]
    float*  step_out = out + (long)V * 64;                    // [V]
    float4* mem_out  = (float4*)(out + (long)V * 64 + V);     // [V*16]
    float4* pow_out  = mem_out + (long)V * 16;                // [V*16]

    int c = cnt[v];
    int o = off[v];
    bool touched = (c > 0);

    // gather-sum gradients for this index
    float4 gs = make_float4(0.f, 0.f, 0.f, 0.f);
    for (int j = 0; j < c; ++j) {
        int r = rowids[o + j];
        float4 g = grad4[(long)r * 16 + q];
        gs.x += g.x; gs.y += g.y; gs.z += g.z; gs.w += g.w;
    }

    float4 e = emb4[t];
    float4 m = mem4[t];
    float4 p = pow4[t];
    float s_old = step_in[v];
    float s_new = touched ? s_old + 1.f : s_old;

    float inv_c = touched ? 1.f / (float)c : 0.f;
    float d1 = touched ? 1.f - exp2f(s_new * LOG2_B1) : 1.f;
    float d2 = touched ? 1.f - exp2f(s_new * LOG2_B2) : 1.f;
    float inv_d1 = 1.f / d1;
    float inv_d2 = 1.f / d2;

    float4 m_new, p_new, e_new;
    {
        float gv, mn, pn, upd;
        gv = gs.x * inv_c;
        mn = touched ? B1 * m.x + (1.f - B1) * gv : m.x;
        pn = touched ? B2 * p.x + (1.f - B2) * gv * gv : p.x;
        upd = LR * (mn * inv_d1) / (sqrtf(pn * inv_d2) + EPSL);
        m_new.x = mn; p_new.x = pn; e_new.x = touched ? e.x - upd : e.x;

        gv = gs.y * inv_c;
        mn = touched ? B1 * m.y + (1.f - B1) * gv : m.y;
        pn = touched ? B2 * p.y + (1.f - B2) * gv * gv : p.y;
        upd = LR * (mn * inv_d1) / (sqrtf(pn * inv_d2) + EPSL);
        m_new.y = mn; p_new.y = pn; e_new.y = touched ? e.y - upd : e.y;

        gv = gs.z * inv_c;
        mn = touched ? B1 * m.z + (1.f - B1) * gv : m.z;
        pn = touched ? B2 * p.z + (1.f - B2) * gv * gv : p.z;
        upd = LR * (mn * inv_d1) / (sqrtf(pn * inv_d2) + EPSL);
        m_new.z = mn; p_new.z = pn; e_new.z = touched ? e.z - upd : e.z;

        gv = gs.w * inv_c;
        mn = touched ? B1 * m.w + (1.f - B1) * gv : m.w;
        pn = touched ? B2 * p.w + (1.f - B2) * gv * gv : p.w;
        upd = LR * (mn * inv_d1) / (sqrtf(pn * inv_d2) + EPSL);
        m_new.w = mn; p_new.w = pn; e_new.w = touched ? e.w - upd : e.w;
    }

    emb_out[t] = e_new;
    mem_out[t] = m_new;
    pow_out[t] = p_new;
    if (q == 0) step_out[v] = s_new;
}

extern "C" void kernel_launch(void* const* d_in, const int* in_sizes, int n_in,
                              void* d_out, int out_size, void* d_ws, size_t ws_size,
                              hipStream_t stream) {
    const int*   idx  = (const int*)  d_in[0];
    const float* grad = (const float*)d_in[1];
    const float* emb  = (const float*)d_in[2];
    const float* step = (const float*)d_in[3];
    const float* mem  = (const float*)d_in[4];
    const float* pw   = (const float*)d_in[5];

    const int N = in_sizes[0];        // 524288
    const int V = in_sizes[3];        // 1000000

    float* out = (float*)d_out;

    // workspace layout (~12.2 MB)
    int* cnt    = (int*)d_ws;          // V
    int* off    = cnt + V;             // V
    int* rowpos = off + V;             // N
    int* rowids = rowpos + N;          // N
    int* bsum   = rowids + N;          // <=1024
    int* bpre   = bsum + 1024;         // <=1024

    const int nB = (V + SCAN_CHUNK - 1) / SCAN_CHUNK;   // 977

    // 1. zero counts
    zero_cnt_kernel<<<1024, 256, 0, stream>>>(cnt, V);
    // 2. count + slot capture
    count_kernel<<<(N + 255) / 256, 256, 0, stream>>>(idx, cnt, rowpos, N);
    // 3-5. exclusive scan of cnt -> off
    block_sum_kernel<<<nB, SCAN_THREADS, 0, stream>>>(cnt, bsum, V);
    scan_bsum_kernel<<<1, 1024, 0, stream>>>(bsum, bpre, nB);
    scan_apply_kernel<<<nB, SCAN_THREADS, 0, stream>>>(cnt, bpre, off, V);
    // 6. fill CSR row ids
    fill_kernel<<<(N + 255) / 256, 256, 0, stream>>>(idx, rowpos, off, rowids, N);
    // 7. fused gather + Adam
    {
        long total = (long)V * 16;
        int threads = 256;
        int blocks = (int)((total + threads - 1) / threads);
        adam_kernel<<<blocks, threads, 0, stream>>>((const float4*)emb, step,
                                                    (const float4*)mem, (const float4*)pw,
                                                    (const float4*)grad,
                                                    cnt, off, rowids, out, V);
    }
}